// Round 21
// baseline (234.555 us; speedup 1.0000x reference)
//
#include <hip/hip_runtime.h>
#include <stdint.h>

#define NB 8
#define NP 100
#define NT 500
#define NV 128
#define NBP 800        // NB*NP
#define TS 512         // tok2 per-path stream stride (u8)
#define ES 500         // eqc per-path stride (16B entries)
#define PAIRS (NB * NT * 25)   // 100000 pair-items
#define NSB 1563       // k_sample sample-role blocks; +NB pq-role blocks

typedef unsigned long long u64;

// rotl via single v_alignbit_b32: alignbit(x,x,32-r) = rotr(x,32-r) = rotl(x,r)
#define ROTL(x, r) __builtin_amdgcn_alignbit((x), (x), 32 - (r))

// padded LDS index: quad offsets {0,32,64,96} -> distinct banks
#define SIDX(v) ((v) + ((v) >> 5))

struct EqPair { u64 e0, e1; };  // little-endian view of uint4 {x|y<<32, z|w<<32}

// ---------------- Threefry-2x32 x4, key = (0,1), interleaved + pinned ----------
// Measured-best variant. Plain-C round-robin chains with a zero-instr asm pin
// per round. Bit-exact per chain.
__device__ __forceinline__ void threefry4_lo(uint32_t cA, uint32_t cB,
                                             uint32_t cC, uint32_t cD,
                                             uint32_t& oA, uint32_t& oB,
                                             uint32_t& oC, uint32_t& oD) {
  const uint32_t K2 = 0x1BD11BDBu;  // k2 = 0x1BD11BDA ^ k0 ^ k1
  uint32_t a0 = 0u, a1 = cA + 1u;   // x0 += k0(0); x1 += k1(1)
  uint32_t b0 = 0u, b1 = cB + 1u;
  uint32_t c0 = 0u, c1 = cC + 1u;
  uint32_t d0 = 0u, d1 = cD + 1u;
#define PIN4() asm volatile("" : "+v"(a1), "+v"(b1), "+v"(c1), "+v"(d1))
#define R4(r) \
  a0 += a1; b0 += b1; c0 += c1; d0 += d1; \
  a1 = ROTL(a1, r) ^ a0; b1 = ROTL(b1, r) ^ b0; \
  c1 = ROTL(c1, r) ^ c0; d1 = ROTL(d1, r) ^ d0; \
  PIN4();
#define K4(kx, ky) \
  a0 += (kx); b0 += (kx); c0 += (kx); d0 += (kx); \
  a1 += (ky); b1 += (ky); c1 += (ky); d1 += (ky);
  R4(13) R4(15) R4(26) R4(6)
  K4(1u, K2 + 1u)                   // x0 += k1; x1 += k2 + 1
  R4(17) R4(29) R4(16) R4(24)
  K4(K2, 2u)                        // x0 += k2; x1 += k0 + 2
  R4(13) R4(15) R4(26) R4(6)
  K4(0u, 4u)                        // x0 += k0; x1 += k1 + 3
  R4(17) R4(29) R4(16) R4(24)
  K4(1u, K2 + 4u)                   // x0 += k1; x1 += k2 + 4
  R4(13) R4(15) R4(26) R4(6)
  oA = a1 + 5u; oB = b1 + 5u;       // x1 += k0 + 5 (final x0 add is dead)
  oC = c1 + 5u; oD = d1 + 5u;
#undef R4
#undef K4
#undef PIN4
}

// ---------------- Kernel 1: Gumbel sampling (ILP-4) + fused pq-table role ------
__global__ __launch_bounds__(256) void k_sample(
    const float* __restrict__ em, const int* __restrict__ elen,
    uint8_t* __restrict__ tok2, float* __restrict__ lp2t,
    const int* __restrict__ labels, const int* __restrict__ llen,
    uint4* __restrict__ pqg) {
  const int tid = threadIdx.x;
  if (blockIdx.x >= NSB) {  // ---- pq role: one block per b ----
    const int b = blockIdx.x - NSB;
    if (tid < NV) {
      const int c = tid;
      const int m = llen[b];  // ref_len in [80,100]
      const int* __restrict__ lab = labels + b * 100;  // L == 100
      uint32_t a0 = 0, a1 = 0, a2 = 0, a3 = 0;
      const int e0 = m < 32 ? m : 32, e1 = m < 64 ? m : 64;
      const int e2 = m < 96 ? m : 96, e3 = m;
      for (int i = 0; i < e0; i++)  a0 |= (uint32_t)(lab[i] == c) << i;
      for (int i = 32; i < e1; i++) a1 |= (uint32_t)(lab[i] == c) << (i - 32);
      for (int i = 64; i < e2; i++) a2 |= (uint32_t)(lab[i] == c) << (i - 64);
      for (int i = 96; i < e3; i++) a3 |= (uint32_t)(lab[i] == c) << (i - 96);
      pqg[b * NV + c] = make_uint4(a0, a1, a2, a3);
    }
    return;
  }
  __shared__ float snw[4][NV + 4];  // padded: SIDX in [0,131]
  const int pi0 = blockIdx.x * 64;            // first pair-item of this block
  const int R0 = pi0 / 25;
  for (int i = tid; i < 4 * NV; i += 256) {   // stage 4 rows
    const int r = i >> 7, v = i & 127;
    int R = R0 + r; R = R < NB * NT ? R : NB * NT - 1;
    snw[r][SIDX(v)] = -__builtin_amdgcn_exp2f(em[(size_t)R * NV + v] * -0.7213475204444817f);
  }
  __syncthreads();
  const int gg = blockIdx.x * 256 + tid;
  const int pitem = gg >> 2, q = gg & 3;
  if (pitem >= PAIRS) return;
  const int R = pitem / 25;
  const int pp = pitem - R * 25;              // [0,25)
  const int b = R / NT;
  const int t = R - b * NT;
  if (t >= elen[b]) return;  // frames beyond length never consumed (quads exit together)
  const int r = R - R0;
  const int vh = q << 5;
  const int sbase = vh + q;                   // SIDX(vh+i) = vh + q + i, i<32
  const int bp0 = b * NP + 4 * pp;
  const uint32_t baseA = ((uint32_t)(bp0 * NT + t) << 7) + (uint32_t)vh;
  const uint32_t baseB = baseA + (uint32_t)(NT << 7);
  const uint32_t baseC = baseB + (uint32_t)(NT << 7);
  const uint32_t baseD = baseC + (uint32_t)(NT << 7);
  const float span = (float)(1.0 - 1e-6) - 1e-6f;
  float bvA = 3.0e38f, bvB = 3.0e38f, bvC = 3.0e38f, bvD = 3.0e38f;
  int biA = 0, biB = 0, biC = 0, biD = 0;
#pragma unroll 8
  for (int i = 0; i < 32; i++) {
    // partitionable threefry: bits[idx] = low output of threefry(key, idx>>32, idx)
    uint32_t rA, rB, rC, rD;
    threefry4_lo(baseA + (uint32_t)i, baseB + (uint32_t)i,
                 baseC + (uint32_t)i, baseD + (uint32_t)i, rA, rB, rC, rD);
    const float w = snw[r][sbase + i];
    const float fA = __uint_as_float((rA >> 9) | 0x3f800000u) - 1.0f;
    const float fB = __uint_as_float((rB >> 9) | 0x3f800000u) - 1.0f;
    const float fC = __uint_as_float((rC >> 9) | 0x3f800000u) - 1.0f;
    const float fD = __uint_as_float((rD >> 9) | 0x3f800000u) - 1.0f;
    const float uA = fmaf(fA, span, 1e-6f);   // clamp dropped: fma >= 1e-6 always
    const float uB = fmaf(fB, span, 1e-6f);
    const float uC = fmaf(fC, span, 1e-6f);
    const float uD = fmaf(fD, span, 1e-6f);
    const float sA = __log2f(uA) * w;         // (-log2 u) * exp(-e/2) > 0
    const float sB = __log2f(uB) * w;
    const float sC = __log2f(uC) * w;
    const float sD = __log2f(uD) * w;
    if (sA < bvA) { bvA = sA; biA = vh + i; } // strict < = first-index tiebreak
    if (sB < bvB) { bvB = sB; biB = vh + i; }
    if (sC < bvC) { bvC = sC; biC = vh + i; }
    if (sD < bvD) { bvD = sD; biD = vh + i; }
  }
  // quad butterfly combine: lower score wins, tie -> lower v
#pragma unroll
  for (int off = 1; off <= 2; off <<= 1) {
    float ov; int oi;
    ov = __shfl_xor(bvA, off); oi = __shfl_xor(biA, off);
    if (ov < bvA || (ov == bvA && oi < biA)) { bvA = ov; biA = oi; }
    ov = __shfl_xor(bvB, off); oi = __shfl_xor(biB, off);
    if (ov < bvB || (ov == bvB && oi < biB)) { bvB = ov; biB = oi; }
    ov = __shfl_xor(bvC, off); oi = __shfl_xor(biC, off);
    if (ov < bvC || (ov == bvC && oi < biC)) { bvC = ov; biC = oi; }
    ov = __shfl_xor(bvD, off); oi = __shfl_xor(biD, off);
    if (ov < bvD || (ov == bvD && oi < biD)) { bvD = ov; biD = oi; }
  }
  if (q == 0) {
    const float* __restrict__ erow = em + (size_t)R * NV;
    const float eA = erow[biA], eB = erow[biB], eC = erow[biC], eD = erow[biD];
    tok2[(size_t)(bp0 + 0) * TS + t] = (uint8_t)biA;
    tok2[(size_t)(bp0 + 1) * TS + t] = (uint8_t)biB;
    tok2[(size_t)(bp0 + 2) * TS + t] = (uint8_t)biC;
    tok2[(size_t)(bp0 + 3) * TS + t] = (uint8_t)biD;
    *(float4*)&lp2t[(size_t)t * NBP + bp0] = make_float4(eA, eB, eC, eD);
  }
}

// ---------------- Kernel 1.5: CTC-collapse compaction of the Eq stream ---------
__global__ __launch_bounds__(64) void k_ce(
    const uint8_t* __restrict__ tok2, const uint4* __restrict__ pqg,
    const int* __restrict__ elen, uint4* __restrict__ eqc,
    int* __restrict__ nkept) {
  __shared__ uint4 pqs[NV];  // 2 KB
  const int bp = blockIdx.x;
  const int b = bp / NP;
  const int lane = threadIdx.x;
  pqs[lane] = pqg[b * NV + lane];
  pqs[lane + 64] = pqg[b * NV + lane + 64];
  __syncthreads();
  const int el = elen[b];  // uniform
  const uint8_t* __restrict__ row = tok2 + (size_t)bp * TS;
  uint4* __restrict__ orow = eqc + (size_t)bp * ES;
  int off = 0;
  for (int t0 = 0; t0 < el; t0 += 64) {
    const int t = t0 + lane;
    const bool inb = (t < el);
    const int c = inb ? row[t] : 0;                  // blank -> not kept
    const int cp = (t == 0) ? 255 : (inb ? row[t - 1] : 255);
    const bool kept = inb && (c != 0) && (c != cp);
    const u64 mask = __ballot(kept);
    const int idx = off + (int)__builtin_amdgcn_mbcnt_hi(
        (uint32_t)(mask >> 32),
        __builtin_amdgcn_mbcnt_lo((uint32_t)mask, 0u));
    if (kept) orow[idx] = pqs[c];
    off += (int)__popcll(mask);
  }
  if (lane == 0) nkept[bp] = off;
}

// ---------------- Kernel 2: Myers edit distance + fused k_red, 512-thr ---------
// Blocks 0..1: dp role, 8 waves/block = 2 waves/SIMD -> co-resident waves
// interleave into each other's dep-latency stalls (dp was dep-bound at
// 1 wave/SIMD: ~280cy/frame vs 140cy issue). Wave w owns path-group B*8+w.
// Blocks 2..9: red role (b = blk-2; k = tid>>7; p = tid&127) — identical
// per-(b,p,k) serial sum as before (same rounding).
__device__ __forceinline__ void loadg(EqPair (&B)[4], int g, const EqPair* __restrict__ rowp) {
#pragma unroll
  for (int i = 0; i < 4; i++) {
    int t = g * 4 + i;
    t = t < ES ? t : ES - 1;
    B[i] = rowp[t];
  }
}

__device__ __forceinline__ void procg(const EqPair (&B)[4], int fbase, int nk,
                                      u64 hmask,
                                      u64& Pv0, u64& Pv1, u64& Mv0, u64& Mv1,
                                      int& score) {
#pragma unroll
  for (int i = 0; i < 4; i++) {
    if (fbase + i >= nk) break;  // per-lane (exec-masked, scalar-pipe cost)
    const u64 Eq0 = B[i].e0;
    const u64 Eq1 = B[i].e1;
    const u64 Xv0 = Eq0 | Mv0, Xv1 = Eq1 | Mv1;
    const u64 EP0 = Eq0 & Pv0, EP1 = Eq1 & Pv1;
    const u64 sA = EP0 + Pv0;
    const u64 sB = EP1 + Pv1 + (sA < EP0 ? 1ull : 0ull);
    const u64 Xh0 = (sA ^ Pv0) | Eq0;
    const u64 Xh1 = (sB ^ Pv1) | Eq1;
    const u64 Ph0 = Mv0 | ~(Xh0 | Pv0);
    const u64 Ph1 = Mv1 | ~(Xh1 | Pv1);
    const u64 Mh0 = Pv0 & Xh0, Mh1 = Pv1 & Xh1;
    score += (int)((Ph1 & hmask) != 0) - (int)((Mh1 & hmask) != 0);
    const u64 nPh1 = (Ph1 << 1) | (Ph0 >> 63);
    const u64 nPh0 = (Ph0 << 1) | 1ull;  // dp[i][0] = i boundary
    const u64 nMh1 = (Mh1 << 1) | (Mh0 >> 63);
    const u64 nMh0 = (Mh0 << 1);
    Pv0 = nMh0 | ~(Xv0 | nPh0);
    Pv1 = nMh1 | ~(Xv1 | nPh1);
    Mv0 = nPh0 & Xv0;
    Mv1 = nPh1 & Xv1;
  }
}

__global__ __launch_bounds__(512) void k_dpred(
    const uint4* __restrict__ eqc, const int* __restrict__ nkept,
    const int* __restrict__ llen, const float* __restrict__ lp2t,
    const int* __restrict__ elen, float* __restrict__ wer,
    double* __restrict__ pred) {
  const int blk = blockIdx.x;
  const int tid = threadIdx.x;
  if (blk >= 2) {  // ---- red role: 8 blocks, b = blk-2, (k, p) from tid ----
    const int b = blk - 2;
    const int k = tid >> 7;          // 0..3 t-chunk
    const int tp = tid & 127;
    const bool active = (tp < NP);
    const int p = active ? tp : NP - 1;
    const int el = elen[b];  // uniform
    const int t0 = k * 125;
    const int t1 = (t0 + 125 < el) ? t0 + 125 : el;
    const float* __restrict__ col = lp2t + b * NP + p;
    double s = 0.0;
#pragma unroll 8
    for (int t = t0; t < t1; t++) s += (double)col[(size_t)t * NBP];
    if (active) pred[(size_t)(b * NP + p) * 4 + k] = s;
    return;
  }
  // ---- dp role: blocks 0..1, wave w owns path-group blk*8+w = (b, h) ----
  const int wave = tid >> 6, lane = tid & 63;
  const int grp = blk * 8 + wave;    // 0..15
  const int b = grp >> 1, h = grp & 1;
  const bool active = (lane < 50);
  const int bp = b * NP + h * 50 + (active ? lane : 49);
  const int m = llen[b];     // ref_len in [80,100] => bit m-1 is in the high word
  const int nk = nkept[bp];  // per-lane hyp length (collapsed)
  const EqPair* __restrict__ rowp = (const EqPair*)(eqc + (size_t)bp * ES);
  u64 Pv0 = ~0ull, Pv1 = ~0ull, Mv0 = 0ull, Mv1 = 0ull;
  int score = m;
  const u64 hmask = 1ull << ((m - 1) & 63);

  const int ngl = (nk + 3) >> 2;
  int ngmax = ngl;           // wave-max group count (uniform prefetch bound)
  for (int off = 1; off < 64; off <<= 1) {
    const int o = __shfl_xor(ngmax, off);
    ngmax = o > ngmax ? o : ngmax;
  }
  EqPair B0[4], B1[4], B2[4], B3[4];
  loadg(B0, 0, rowp); loadg(B1, 1, rowp);
  loadg(B2, 2, rowp); loadg(B3, 3, rowp);
  int g = 0;
  while (g + 4 <= ngmax) {
    procg(B0, (g    ) * 4, nk, hmask, Pv0, Pv1, Mv0, Mv1, score);
    loadg(B0, g + 4, rowp);
    procg(B1, (g + 1) * 4, nk, hmask, Pv0, Pv1, Mv0, Mv1, score);
    loadg(B1, g + 5, rowp);
    procg(B2, (g + 2) * 4, nk, hmask, Pv0, Pv1, Mv0, Mv1, score);
    loadg(B2, g + 6, rowp);
    procg(B3, (g + 3) * 4, nk, hmask, Pv0, Pv1, Mv0, Mv1, score);
    loadg(B3, g + 7, rowp);
    g += 4;
  }
  if (g     < ngmax) procg(B0, (g    ) * 4, nk, hmask, Pv0, Pv1, Mv0, Mv1, score);
  if (g + 1 < ngmax) procg(B1, (g + 1) * 4, nk, hmask, Pv0, Pv1, Mv0, Mv1, score);
  if (g + 2 < ngmax) procg(B2, (g + 2) * 4, nk, hmask, Pv0, Pv1, Mv0, Mv1, score);
  if (active) wer[bp] = (float)score;
}

// ---------------- Kernel 3: per-b softmax + expected WER + mean ----------------
__global__ __launch_bounds__(512) void k_fin(
    const double* __restrict__ pred, const float* __restrict__ wer,
    float* __restrict__ out) {
  __shared__ float partial[NB];
  const int w = threadIdx.x >> 6, lane = threadIdx.x & 63;  // w = b
  const int base = w * NP;
  float l0 = -1e30f, l1 = -1e30f;
  if (lane < NP) {
    const double* pr = pred + (size_t)(base + lane) * 4;
    l0 = (float)(pr[0] + pr[1] + pr[2] + pr[3]);
  }
  if (lane + 64 < NP) {
    const double* pr = pred + (size_t)(base + lane + 64) * 4;
    l1 = (float)(pr[0] + pr[1] + pr[2] + pr[3]);
  }
  float mx = fmaxf(l0, l1);
  for (int off = 1; off < 64; off <<= 1) mx = fmaxf(mx, __shfl_xor(mx, off));
  const float e0 = (lane < NP) ? __expf(l0 - mx) : 0.0f;
  const float e1 = (lane + 64 < NP) ? __expf(l1 - mx) : 0.0f;
  const float w0 = (lane < NP) ? wer[base + lane] : 0.0f;
  const float w1 = (lane + 64 < NP) ? wer[base + lane + 64] : 0.0f;
  float s = e0 + e1;
  float a = e0 * w0 + e1 * w1;
  for (int off = 1; off < 64; off <<= 1) {
    s += __shfl_xor(s, off);
    a += __shfl_xor(a, off);
  }
  if (lane == 0) partial[w] = a / s;
  __syncthreads();
  if (threadIdx.x == 0) {
    float tot = 0.0f;
    for (int i = 0; i < NB; i++) tot += partial[i];
    out[0] = tot * (1.0f / (float)NBP);
  }
}

extern "C" void kernel_launch(void* const* d_in, const int* in_sizes, int n_in,
                              void* d_out, int out_size, void* d_ws, size_t ws_size,
                              hipStream_t stream) {
  const float* em     = (const float*)d_in[0];
  const int*   elen   = (const int*)d_in[1];
  const int*   labels = (const int*)d_in[2];
  const int*   llen   = (const int*)d_in[3];
  float* out = (float*)d_out;
  char* ws = (char*)d_ws;
  uint4*   eqc   = (uint4*)ws;                        // 800*500*16 = 6,400,000
  uint8_t* tok2  = (uint8_t*)(ws + 6400000);          // 409,600
  float*   lp2t  = (float*)(ws + 6809600);            // 1,600,000 ([t][bp])
  float*   wer   = (float*)(ws + 8409600);            // 3,200
  double*  pred  = (double*)(ws + 8412800);           // 25,600
  int*     nkept = (int*)(ws + 8438400);              // 3,200
  uint4*   pqg   = (uint4*)(ws + 8441600);            // 16,384

  k_sample<<<dim3(NSB + NB), dim3(256), 0, stream>>>(em, elen, tok2, lp2t,
                                                     labels, llen, pqg);
  k_ce<<<dim3(NBP), dim3(64), 0, stream>>>(tok2, pqg, elen, eqc, nkept);
  k_dpred<<<dim3(10), dim3(512), 0, stream>>>(eqc, nkept, llen, lp2t, elen, wer, pred);
  k_fin<<<dim3(1), dim3(512), 0, stream>>>(pred, wer, out);
}

// Round 22
// 185.953 us; speedup vs baseline: 1.2614x; 1.2614x over previous
//
#include <hip/hip_runtime.h>
#include <stdint.h>

#define NB 8
#define NP 100
#define NT 500
#define NV 128
#define NBP 800        // NB*NP
#define TS 512         // tok2 per-path stream stride (u8)
#define ES 500         // eqc per-path stride (16B entries)
#define PAIRS (NB * NT * 25)   // 100000 pair-items
#define NSB 1563       // k_sample sample-role blocks; +NB pq-role blocks

typedef unsigned long long u64;

// rotl via single v_alignbit_b32: alignbit(x,x,32-r) = rotr(x,32-r) = rotl(x,r)
#define ROTL(x, r) __builtin_amdgcn_alignbit((x), (x), 32 - (r))

// padded LDS index: quad offsets {0,32,64,96} -> distinct banks
#define SIDX(v) ((v) + ((v) >> 5))

struct EqPair { u64 e0, e1; };  // little-endian view of uint4 {x|y<<32, z|w<<32}

// ---------------- Threefry-2x32 x4, key = (0,1), interleaved + pinned ----------
// Measured-best variant (R20: 186.2us total). Plain-C round-robin chains with
// a zero-instr asm pin per round. Bit-exact per chain.
__device__ __forceinline__ void threefry4_lo(uint32_t cA, uint32_t cB,
                                             uint32_t cC, uint32_t cD,
                                             uint32_t& oA, uint32_t& oB,
                                             uint32_t& oC, uint32_t& oD) {
  const uint32_t K2 = 0x1BD11BDBu;  // k2 = 0x1BD11BDA ^ k0 ^ k1
  uint32_t a0 = 0u, a1 = cA + 1u;   // x0 += k0(0); x1 += k1(1)
  uint32_t b0 = 0u, b1 = cB + 1u;
  uint32_t c0 = 0u, c1 = cC + 1u;
  uint32_t d0 = 0u, d1 = cD + 1u;
#define PIN4() asm volatile("" : "+v"(a1), "+v"(b1), "+v"(c1), "+v"(d1))
#define R4(r) \
  a0 += a1; b0 += b1; c0 += c1; d0 += d1; \
  a1 = ROTL(a1, r) ^ a0; b1 = ROTL(b1, r) ^ b0; \
  c1 = ROTL(c1, r) ^ c0; d1 = ROTL(d1, r) ^ d0; \
  PIN4();
#define K4(kx, ky) \
  a0 += (kx); b0 += (kx); c0 += (kx); d0 += (kx); \
  a1 += (ky); b1 += (ky); c1 += (ky); d1 += (ky);
  R4(13) R4(15) R4(26) R4(6)
  K4(1u, K2 + 1u)                   // x0 += k1; x1 += k2 + 1
  R4(17) R4(29) R4(16) R4(24)
  K4(K2, 2u)                        // x0 += k2; x1 += k0 + 2
  R4(13) R4(15) R4(26) R4(6)
  K4(0u, 4u)                        // x0 += k0; x1 += k1 + 3
  R4(17) R4(29) R4(16) R4(24)
  K4(1u, K2 + 4u)                   // x0 += k1; x1 += k2 + 4
  R4(13) R4(15) R4(26) R4(6)
  oA = a1 + 5u; oB = b1 + 5u;       // x1 += k0 + 5 (final x0 add is dead)
  oC = c1 + 5u; oD = d1 + 5u;
#undef R4
#undef K4
#undef PIN4
}

// ---------------- Kernel 1: Gumbel sampling (ILP-4) + fused pq-table role ------
__global__ __launch_bounds__(256) void k_sample(
    const float* __restrict__ em, const int* __restrict__ elen,
    uint8_t* __restrict__ tok2, float* __restrict__ lp2t,
    const int* __restrict__ labels, const int* __restrict__ llen,
    uint4* __restrict__ pqg) {
  const int tid = threadIdx.x;
  if (blockIdx.x >= NSB) {  // ---- pq role: one block per b ----
    const int b = blockIdx.x - NSB;
    if (tid < NV) {
      const int c = tid;
      const int m = llen[b];  // ref_len in [80,100]
      const int* __restrict__ lab = labels + b * 100;  // L == 100
      uint32_t a0 = 0, a1 = 0, a2 = 0, a3 = 0;
      const int e0 = m < 32 ? m : 32, e1 = m < 64 ? m : 64;
      const int e2 = m < 96 ? m : 96, e3 = m;
      for (int i = 0; i < e0; i++)  a0 |= (uint32_t)(lab[i] == c) << i;
      for (int i = 32; i < e1; i++) a1 |= (uint32_t)(lab[i] == c) << (i - 32);
      for (int i = 64; i < e2; i++) a2 |= (uint32_t)(lab[i] == c) << (i - 64);
      for (int i = 96; i < e3; i++) a3 |= (uint32_t)(lab[i] == c) << (i - 96);
      pqg[b * NV + c] = make_uint4(a0, a1, a2, a3);
    }
    return;
  }
  __shared__ float snw[4][NV + 4];  // padded: SIDX in [0,131]
  const int pi0 = blockIdx.x * 64;            // first pair-item of this block
  const int R0 = pi0 / 25;
  for (int i = tid; i < 4 * NV; i += 256) {   // stage 4 rows
    const int r = i >> 7, v = i & 127;
    int R = R0 + r; R = R < NB * NT ? R : NB * NT - 1;
    snw[r][SIDX(v)] = -__builtin_amdgcn_exp2f(em[(size_t)R * NV + v] * -0.7213475204444817f);
  }
  __syncthreads();
  const int gg = blockIdx.x * 256 + tid;
  const int pitem = gg >> 2, q = gg & 3;
  if (pitem >= PAIRS) return;
  const int R = pitem / 25;
  const int pp = pitem - R * 25;              // [0,25)
  const int b = R / NT;
  const int t = R - b * NT;
  if (t >= elen[b]) return;  // frames beyond length never consumed (quads exit together)
  const int r = R - R0;
  const int vh = q << 5;
  const int sbase = vh + q;                   // SIDX(vh+i) = vh + q + i, i<32
  const int bp0 = b * NP + 4 * pp;
  const uint32_t baseA = ((uint32_t)(bp0 * NT + t) << 7) + (uint32_t)vh;
  const uint32_t baseB = baseA + (uint32_t)(NT << 7);
  const uint32_t baseC = baseB + (uint32_t)(NT << 7);
  const uint32_t baseD = baseC + (uint32_t)(NT << 7);
  const float span = (float)(1.0 - 1e-6) - 1e-6f;
  float bvA = 3.0e38f, bvB = 3.0e38f, bvC = 3.0e38f, bvD = 3.0e38f;
  int biA = 0, biB = 0, biC = 0, biD = 0;
#pragma unroll 8
  for (int i = 0; i < 32; i++) {
    // partitionable threefry: bits[idx] = low output of threefry(key, idx>>32, idx)
    uint32_t rA, rB, rC, rD;
    threefry4_lo(baseA + (uint32_t)i, baseB + (uint32_t)i,
                 baseC + (uint32_t)i, baseD + (uint32_t)i, rA, rB, rC, rD);
    const float w = snw[r][sbase + i];
    const float fA = __uint_as_float((rA >> 9) | 0x3f800000u) - 1.0f;
    const float fB = __uint_as_float((rB >> 9) | 0x3f800000u) - 1.0f;
    const float fC = __uint_as_float((rC >> 9) | 0x3f800000u) - 1.0f;
    const float fD = __uint_as_float((rD >> 9) | 0x3f800000u) - 1.0f;
    const float uA = fmaf(fA, span, 1e-6f);   // clamp dropped: fma >= 1e-6 always
    const float uB = fmaf(fB, span, 1e-6f);
    const float uC = fmaf(fC, span, 1e-6f);
    const float uD = fmaf(fD, span, 1e-6f);
    const float sA = __log2f(uA) * w;         // (-log2 u) * exp(-e/2) > 0
    const float sB = __log2f(uB) * w;
    const float sC = __log2f(uC) * w;
    const float sD = __log2f(uD) * w;
    if (sA < bvA) { bvA = sA; biA = vh + i; } // strict < = first-index tiebreak
    if (sB < bvB) { bvB = sB; biB = vh + i; }
    if (sC < bvC) { bvC = sC; biC = vh + i; }
    if (sD < bvD) { bvD = sD; biD = vh + i; }
  }
  // quad butterfly combine: lower score wins, tie -> lower v
#pragma unroll
  for (int off = 1; off <= 2; off <<= 1) {
    float ov; int oi;
    ov = __shfl_xor(bvA, off); oi = __shfl_xor(biA, off);
    if (ov < bvA || (ov == bvA && oi < biA)) { bvA = ov; biA = oi; }
    ov = __shfl_xor(bvB, off); oi = __shfl_xor(biB, off);
    if (ov < bvB || (ov == bvB && oi < biB)) { bvB = ov; biB = oi; }
    ov = __shfl_xor(bvC, off); oi = __shfl_xor(biC, off);
    if (ov < bvC || (ov == bvC && oi < biC)) { bvC = ov; biC = oi; }
    ov = __shfl_xor(bvD, off); oi = __shfl_xor(biD, off);
    if (ov < bvD || (ov == bvD && oi < biD)) { bvD = ov; biD = oi; }
  }
  if (q == 0) {
    const float* __restrict__ erow = em + (size_t)R * NV;
    const float eA = erow[biA], eB = erow[biB], eC = erow[biC], eD = erow[biD];
    tok2[(size_t)(bp0 + 0) * TS + t] = (uint8_t)biA;
    tok2[(size_t)(bp0 + 1) * TS + t] = (uint8_t)biB;
    tok2[(size_t)(bp0 + 2) * TS + t] = (uint8_t)biC;
    tok2[(size_t)(bp0 + 3) * TS + t] = (uint8_t)biD;
    *(float4*)&lp2t[(size_t)t * NBP + bp0] = make_float4(eA, eB, eC, eD);
  }
}

// ---------------- Kernel 1.5: CTC-collapse compaction of the Eq stream ---------
__global__ __launch_bounds__(64) void k_ce(
    const uint8_t* __restrict__ tok2, const uint4* __restrict__ pqg,
    const int* __restrict__ elen, uint4* __restrict__ eqc,
    int* __restrict__ nkept) {
  __shared__ uint4 pqs[NV];  // 2 KB
  const int bp = blockIdx.x;
  const int b = bp / NP;
  const int lane = threadIdx.x;
  pqs[lane] = pqg[b * NV + lane];
  pqs[lane + 64] = pqg[b * NV + lane + 64];
  __syncthreads();
  const int el = elen[b];  // uniform
  const uint8_t* __restrict__ row = tok2 + (size_t)bp * TS;
  uint4* __restrict__ orow = eqc + (size_t)bp * ES;
  int off = 0;
  for (int t0 = 0; t0 < el; t0 += 64) {
    const int t = t0 + lane;
    const bool inb = (t < el);
    const int c = inb ? row[t] : 0;                  // blank -> not kept
    const int cp = (t == 0) ? 255 : (inb ? row[t - 1] : 255);
    const bool kept = inb && (c != 0) && (c != cp);
    const u64 mask = __ballot(kept);
    const int idx = off + (int)__builtin_amdgcn_mbcnt_hi(
        (uint32_t)(mask >> 32),
        __builtin_amdgcn_mbcnt_lo((uint32_t)mask, 0u));
    if (kept) orow[idx] = pqs[c];
    off += (int)__popcll(mask);
  }
  if (lane == 0) nkept[bp] = off;
}

// ---------------- Kernel 2: Myers edit distance (R12 body) + fused k_red -------
// Blocks 0..15: dp role (R12-exact guard; 1 wave per CU — R21 proved each dp
// wave saturates its SIMD issue port, so 2 waves/SIMD halves throughput).
// Blocks 16..47: logp partial-sum role (coalesced [t][bp] reads, f64).
__device__ __forceinline__ void loadg(EqPair (&B)[4], int g, const EqPair* __restrict__ rowp) {
#pragma unroll
  for (int i = 0; i < 4; i++) {
    int t = g * 4 + i;
    t = t < ES ? t : ES - 1;
    B[i] = rowp[t];
  }
}

__device__ __forceinline__ void procg(const EqPair (&B)[4], int fbase, int nk,
                                      u64 hmask,
                                      u64& Pv0, u64& Pv1, u64& Mv0, u64& Mv1,
                                      int& score) {
#pragma unroll
  for (int i = 0; i < 4; i++) {
    if (fbase + i >= nk) break;  // per-lane (exec-masked, scalar-pipe cost)
    const u64 Eq0 = B[i].e0;
    const u64 Eq1 = B[i].e1;
    const u64 Xv0 = Eq0 | Mv0, Xv1 = Eq1 | Mv1;
    const u64 EP0 = Eq0 & Pv0, EP1 = Eq1 & Pv1;
    const u64 sA = EP0 + Pv0;
    const u64 sB = EP1 + Pv1 + (sA < EP0 ? 1ull : 0ull);
    const u64 Xh0 = (sA ^ Pv0) | Eq0;
    const u64 Xh1 = (sB ^ Pv1) | Eq1;
    const u64 Ph0 = Mv0 | ~(Xh0 | Pv0);
    const u64 Ph1 = Mv1 | ~(Xh1 | Pv1);
    const u64 Mh0 = Pv0 & Xh0, Mh1 = Pv1 & Xh1;
    score += (int)((Ph1 & hmask) != 0) - (int)((Mh1 & hmask) != 0);
    const u64 nPh1 = (Ph1 << 1) | (Ph0 >> 63);
    const u64 nPh0 = (Ph0 << 1) | 1ull;  // dp[i][0] = i boundary
    const u64 nMh1 = (Mh1 << 1) | (Mh0 >> 63);
    const u64 nMh0 = (Mh0 << 1);
    Pv0 = nMh0 | ~(Xv0 | nPh0);
    Pv1 = nMh1 | ~(Xv1 | nPh1);
    Mv0 = nPh0 & Xv0;
    Mv1 = nPh1 & Xv1;
  }
}

__global__ __launch_bounds__(128) void k_dpred(
    const uint4* __restrict__ eqc, const int* __restrict__ nkept,
    const int* __restrict__ llen, const float* __restrict__ lp2t,
    const int* __restrict__ elen, float* __restrict__ wer,
    double* __restrict__ pred) {
  const int blk = blockIdx.x;
  const int tid = threadIdx.x;
  if (blk >= 16) {  // ---- red role: 32 blocks, (b, t-chunk k) ----
    const int i = blk - 16;
    const int b = i >> 2, k = i & 3;
    const bool active = (tid < NP);
    const int p = active ? tid : NP - 1;
    const int el = elen[b];  // uniform
    const int t0 = k * 125;
    const int t1 = (t0 + 125 < el) ? t0 + 125 : el;
    const float* __restrict__ col = lp2t + b * NP + p;
    double s = 0.0;
#pragma unroll 8
    for (int t = t0; t < t1; t++) s += (double)col[(size_t)t * NBP];
    if (active) pred[(size_t)(b * NP + p) * 4 + k] = s;
    return;
  }
  // ---- dp role: blocks 0..15 = (b, half); only wave 0 works ----
  if (tid >= 64) return;
  const int b = blk >> 1, h = blk & 1;
  const bool active = (tid < 50);
  const int bp = b * NP + h * 50 + (active ? tid : 49);
  const int m = llen[b];     // ref_len in [80,100] => bit m-1 is in the high word
  const int nk = nkept[bp];  // per-lane hyp length (collapsed)
  const EqPair* __restrict__ rowp = (const EqPair*)(eqc + (size_t)bp * ES);
  u64 Pv0 = ~0ull, Pv1 = ~0ull, Mv0 = 0ull, Mv1 = 0ull;
  int score = m;
  const u64 hmask = 1ull << ((m - 1) & 63);

  const int ngl = (nk + 3) >> 2;
  int ngmax = ngl;           // wave-max group count (uniform prefetch bound)
  for (int off = 1; off < 64; off <<= 1) {
    const int o = __shfl_xor(ngmax, off);
    ngmax = o > ngmax ? o : ngmax;
  }
  EqPair B0[4], B1[4], B2[4], B3[4];
  loadg(B0, 0, rowp); loadg(B1, 1, rowp);
  loadg(B2, 2, rowp); loadg(B3, 3, rowp);
  int g = 0;
  while (g + 4 <= ngmax) {
    procg(B0, (g    ) * 4, nk, hmask, Pv0, Pv1, Mv0, Mv1, score);
    loadg(B0, g + 4, rowp);
    procg(B1, (g + 1) * 4, nk, hmask, Pv0, Pv1, Mv0, Mv1, score);
    loadg(B1, g + 5, rowp);
    procg(B2, (g + 2) * 4, nk, hmask, Pv0, Pv1, Mv0, Mv1, score);
    loadg(B2, g + 6, rowp);
    procg(B3, (g + 3) * 4, nk, hmask, Pv0, Pv1, Mv0, Mv1, score);
    loadg(B3, g + 7, rowp);
    g += 4;
  }
  if (g     < ngmax) procg(B0, (g    ) * 4, nk, hmask, Pv0, Pv1, Mv0, Mv1, score);
  if (g + 1 < ngmax) procg(B1, (g + 1) * 4, nk, hmask, Pv0, Pv1, Mv0, Mv1, score);
  if (g + 2 < ngmax) procg(B2, (g + 2) * 4, nk, hmask, Pv0, Pv1, Mv0, Mv1, score);
  if (active) wer[bp] = (float)score;
}

// ---------------- Kernel 3: per-b softmax + expected WER + mean ----------------
__global__ __launch_bounds__(512) void k_fin(
    const double* __restrict__ pred, const float* __restrict__ wer,
    float* __restrict__ out) {
  __shared__ float partial[NB];
  const int w = threadIdx.x >> 6, lane = threadIdx.x & 63;  // w = b
  const int base = w * NP;
  float l0 = -1e30f, l1 = -1e30f;
  if (lane < NP) {
    const double* pr = pred + (size_t)(base + lane) * 4;
    l0 = (float)(pr[0] + pr[1] + pr[2] + pr[3]);
  }
  if (lane + 64 < NP) {
    const double* pr = pred + (size_t)(base + lane + 64) * 4;
    l1 = (float)(pr[0] + pr[1] + pr[2] + pr[3]);
  }
  float mx = fmaxf(l0, l1);
  for (int off = 1; off < 64; off <<= 1) mx = fmaxf(mx, __shfl_xor(mx, off));
  const float e0 = (lane < NP) ? __expf(l0 - mx) : 0.0f;
  const float e1 = (lane + 64 < NP) ? __expf(l1 - mx) : 0.0f;
  const float w0 = (lane < NP) ? wer[base + lane] : 0.0f;
  const float w1 = (lane + 64 < NP) ? wer[base + lane + 64] : 0.0f;
  float s = e0 + e1;
  float a = e0 * w0 + e1 * w1;
  for (int off = 1; off < 64; off <<= 1) {
    s += __shfl_xor(s, off);
    a += __shfl_xor(a, off);
  }
  if (lane == 0) partial[w] = a / s;
  __syncthreads();
  if (threadIdx.x == 0) {
    float tot = 0.0f;
    for (int i = 0; i < NB; i++) tot += partial[i];
    out[0] = tot * (1.0f / (float)NBP);
  }
}

extern "C" void kernel_launch(void* const* d_in, const int* in_sizes, int n_in,
                              void* d_out, int out_size, void* d_ws, size_t ws_size,
                              hipStream_t stream) {
  const float* em     = (const float*)d_in[0];
  const int*   elen   = (const int*)d_in[1];
  const int*   labels = (const int*)d_in[2];
  const int*   llen   = (const int*)d_in[3];
  float* out = (float*)d_out;
  char* ws = (char*)d_ws;
  uint4*   eqc   = (uint4*)ws;                        // 800*500*16 = 6,400,000
  uint8_t* tok2  = (uint8_t*)(ws + 6400000);          // 409,600
  float*   lp2t  = (float*)(ws + 6809600);            // 1,600,000 ([t][bp])
  float*   wer   = (float*)(ws + 8409600);            // 3,200
  double*  pred  = (double*)(ws + 8412800);           // 25,600
  int*     nkept = (int*)(ws + 8438400);              // 3,200
  uint4*   pqg   = (uint4*)(ws + 8441600);            // 16,384

  k_sample<<<dim3(NSB + NB), dim3(256), 0, stream>>>(em, elen, tok2, lp2t,
                                                     labels, llen, pqg);
  k_ce<<<dim3(NBP), dim3(64), 0, stream>>>(tok2, pqg, elen, eqc, nkept);
  k_dpred<<<dim3(48), dim3(128), 0, stream>>>(eqc, nkept, llen, lp2t, elen, wer, pred);
  k_fin<<<dim3(1), dim3(512), 0, stream>>>(pred, wer, out);
}